// Round 5
// baseline (1487.089 us; speedup 1.0000x reference)
//
#include <hip/hip_runtime.h>
#include <math.h>

// Shapes (fixed): H=8, D=256, HD=32, B=16, Q=512, S1=64, NTASK=448
typedef _Float16 f16;
typedef f16  f16x8 __attribute__((ext_vector_type(8)));
typedef f16  f16x4 __attribute__((ext_vector_type(4)));
typedef float f32x4 __attribute__((ext_vector_type(4)));

// ---------------------------------------------------------------------------
// Projection GEMM (fp32 compute, fp16 output).
// Normal outputs: [h][b][n][32] fp16 row-major.  V output (p==vt_p): V^T
// layout [h][b][e][NR] fp16 (contiguous m) for MFMA A-fragments.
// ---------------------------------------------------------------------------
__global__ __launch_bounds__(256)
void proj_gemm(const float* __restrict__ A,
               const float* __restrict__ W0, const float* __restrict__ W1p,
               const float* __restrict__ W2p, const float* __restrict__ W3p,
               f16* __restrict__ O0, f16* __restrict__ O1,
               f16* __restrict__ O2, f16* __restrict__ O3,
               int q_off, int rows_per_b, int tiles_per_b, int vt_p)
{
    __shared__ float Asub[32][68];
    __shared__ float Bsub[32][68];
    const int tid = (int)threadIdx.x;
    const int b  = (int)blockIdx.x / tiles_per_b;
    const int n0 = ((int)blockIdx.x % tiles_per_b) * 64;
    const int p  = (int)blockIdx.y >> 2;
    const int cb = ((int)blockIdx.y & 3) * 64;
    const float* Wp = (p == 0) ? W0 : (p == 1) ? W1p : (p == 2) ? W2p : W3p;
    f16* Op         = (p == 0) ? O0 : (p == 1) ? O1 : (p == 2) ? O2 : O3;

    const int tx = tid & 15, ty = tid >> 4;
    float acc[4][4] = {};
    const float* Arow = A + (size_t)(b * 512 + q_off + n0) * 256;

    for (int k0 = 0; k0 < 256; k0 += 32) {
        #pragma unroll
        for (int i = 0; i < 8; ++i) {
            int idx = tid + 256 * i;
            int kk = idx & 31, r = idx >> 5;
            Asub[kk][r] = Arow[(size_t)r * 256 + k0 + kk];
        }
        #pragma unroll
        for (int i = 0; i < 8; ++i) {
            int idx = tid + 256 * i;
            int c = idx & 63, kk = idx >> 6;
            int cg = cb + c;
            int h = cg >> 5, e = cg & 31;
            Bsub[kk][c] = Wp[(size_t)(h * 256 + k0 + kk) * 32 + e];
        }
        __syncthreads();
        #pragma unroll
        for (int kk = 0; kk < 32; ++kk) {
            float4 a4 = *(const float4*)&Asub[kk][ty * 4];
            float4 b4 = *(const float4*)&Bsub[kk][tx * 4];
            acc[0][0] += a4.x * b4.x; acc[0][1] += a4.x * b4.y; acc[0][2] += a4.x * b4.z; acc[0][3] += a4.x * b4.w;
            acc[1][0] += a4.y * b4.x; acc[1][1] += a4.y * b4.y; acc[1][2] += a4.y * b4.z; acc[1][3] += a4.y * b4.w;
            acc[2][0] += a4.z * b4.x; acc[2][1] += a4.z * b4.y; acc[2][2] += a4.z * b4.z; acc[2][3] += a4.z * b4.w;
            acc[3][0] += a4.w * b4.x; acc[3][1] += a4.w * b4.y; acc[3][2] += a4.w * b4.z; acc[3][3] += a4.w * b4.w;
        }
        __syncthreads();
    }
    const int cg = cb + tx * 4;
    const int h = cg >> 5, e = cg & 31;
    if (p == vt_p) {
        #pragma unroll
        for (int i = 0; i < 4; ++i) {
            int n = n0 + ty * 4 + i;
            #pragma unroll
            for (int j = 0; j < 4; ++j)
                Op[(((size_t)h * 16 + b) * 32 + e + j) * rows_per_b + n] = (f16)acc[i][j];
        }
    } else {
        #pragma unroll
        for (int i = 0; i < 4; ++i) {
            int n = n0 + ty * 4 + i;
            f16x4 v = { (f16)acc[i][0], (f16)acc[i][1], (f16)acc[i][2], (f16)acc[i][3] };
            *(f16x4*)&Op[(((size_t)h * 16 + b) * rows_per_b + n) * 32 + e] = v;
        }
    }
}

// ---------------------------------------------------------------------------
// Output projection: C[bq][d] = HEADS[8192,256] @ W_out[256,256]  (fp32)
// ---------------------------------------------------------------------------
__global__ __launch_bounds__(256)
void out_gemm(const float* __restrict__ A, const float* __restrict__ Bm,
              float* __restrict__ C)
{
    __shared__ float Asub[32][68];
    __shared__ float Bsub[32][68];
    const int tid = (int)threadIdx.x;
    const int row0 = (int)blockIdx.x * 64;
    const int col0 = (int)blockIdx.y * 64;
    const int tx = tid & 15, ty = tid >> 4;
    float acc[4][4] = {};

    for (int k0 = 0; k0 < 256; k0 += 32) {
        #pragma unroll
        for (int i = 0; i < 8; ++i) {
            int idx = tid + 256 * i;
            int kk = idx & 31, r = idx >> 5;
            Asub[kk][r] = A[(size_t)(row0 + r) * 256 + k0 + kk];
        }
        #pragma unroll
        for (int i = 0; i < 8; ++i) {
            int idx = tid + 256 * i;
            int c = idx & 63, kk = idx >> 6;
            Bsub[kk][c] = Bm[(size_t)(k0 + kk) * 256 + col0 + c];
        }
        __syncthreads();
        #pragma unroll
        for (int kk = 0; kk < 32; ++kk) {
            float4 a4 = *(const float4*)&Asub[kk][ty * 4];
            float4 b4 = *(const float4*)&Bsub[kk][tx * 4];
            acc[0][0] += a4.x * b4.x; acc[0][1] += a4.x * b4.y; acc[0][2] += a4.x * b4.z; acc[0][3] += a4.x * b4.w;
            acc[1][0] += a4.y * b4.x; acc[1][1] += a4.y * b4.y; acc[1][2] += a4.y * b4.z; acc[1][3] += a4.y * b4.w;
            acc[2][0] += a4.z * b4.x; acc[2][1] += a4.z * b4.y; acc[2][2] += a4.z * b4.z; acc[2][3] += a4.z * b4.w;
            acc[3][0] += a4.w * b4.x; acc[3][1] += a4.w * b4.y; acc[3][2] += a4.w * b4.z; acc[3][3] += a4.w * b4.w;
        }
        __syncthreads();
    }
    #pragma unroll
    for (int i = 0; i < 4; ++i) {
        float4 v = make_float4(acc[i][0], acc[i][1], acc[i][2], acc[i][3]);
        *(float4*)&C[(size_t)(row0 + ty * 4 + i) * 256 + col0 + tx * 4] = v;
    }
}

// ---------------------------------------------------------------------------
// Unified wave-autonomous attend. One WAVE = one (n-tile, b, 64-key chunk) of
// one of the three attention passes. NO barriers in the K-loop.
// Scores computed transposed: S^T = K·Q^T (A=K-frag, B=Q-frag) so the C-layout
// (n=lane&15, m=qd*4+r) is directly the B-fragment for O^T = V^T·P.
// Per-lane state: row n=ln -> M[8], L[8]; oacc[h][etile] f32x4 (e=qd*4+r).
// Writes unnormalized o (f16) + (m,l) per row; merged by combine_kernel.
// ---------------------------------------------------------------------------
__global__ __launch_bounds__(256, 2)
void attend_fused(const f16* __restrict__ QT1, const f16* __restrict__ QT,
                  const f16* __restrict__ QS,  const f16* __restrict__ KC,
                  const f16* __restrict__ VCT, const f16* __restrict__ KS,
                  const f16* __restrict__ VST, const float* __restrict__ aux,
                  const float* __restrict__ W1g, const float* __restrict__ b1g,
                  const float* __restrict__ W2g, const float* __restrict__ b2g,
                  f16* __restrict__ oA, float* __restrict__ mlA,
                  f16* __restrict__ oB, float* __restrict__ mlB,
                  f16* __restrict__ oC, float* __restrict__ mlC)
{
    __shared__ float Wl[408];   // W1(256) | W2(128) | b1(16) | b2(8)
    const int tid = (int)threadIdx.x;
    Wl[tid] = W1g[tid];
    if (tid < 128) Wl[256 + tid] = W2g[tid];
    if (tid < 16)  Wl[384 + tid] = b1g[tid];
    if (tid < 8)   Wl[400 + tid] = b2g[tid];
    __syncthreads();

    const int wid  = (int)blockIdx.x * 4 + (tid >> 6);
    const int lane = tid & 63;
    const int ln   = lane & 15;        // row n within tile (scores C-layout col)
    const int qd   = lane >> 4;        // quad: m = qd*4+r (scores), e = qd*4+r (O^T)

    // ---- decode work item ----
    const f16 *Qb, *Kb, *Vt;
    f16* op; float* mlo;
    int NR, ML, n_off, m_off, m_base, n0, b;
    if (wid < 3136) {                       // attend1: task q vs task k
        int c = wid / 448, rem = wid % 448;
        n0 = (rem / 16) * 16; b = rem % 16;
        Qb = QT1; Kb = KC; Vt = VCT; NR = 448; ML = 448; n_off = 64; m_off = 64;
        m_base = c * 64;
        op  = oA  + (size_t)c * 8 * 16 * 448 * 32;
        mlo = mlA + (size_t)c * 8 * 16 * 448 * 2;
    } else if (wid < 3584) {                // attend2: task q vs stat k
        int rem = wid - 3136;
        n0 = (rem / 16) * 16; b = rem % 16;
        Qb = QT; Kb = KS; Vt = VST; NR = 448; ML = 64; n_off = 64; m_off = 0;
        m_base = 0;
        op = oB; mlo = mlB;
    } else {                                // attend3: stat q vs task k
        int rem = wid - 3584;
        int c = rem / 64, r2 = rem % 64;
        n0 = (r2 / 16) * 16; b = r2 % 16;
        Qb = QS; Kb = KC; Vt = VCT; NR = 64; ML = 448; n_off = 0; m_off = 64;
        m_base = c * 64;
        op  = oC  + (size_t)c * 8 * 16 * 64 * 32;
        mlo = mlC + (size_t)c * 8 * 16 * 64 * 2;
    }

    const size_t aux_base = ((size_t)b * 512 + (n_off + n0 + ln)) * 512 + m_off;

    f32x4 oacc[8][2];
    #pragma unroll
    for (int h = 0; h < 8; ++h) { oacc[h][0] = (f32x4){0,0,0,0}; oacc[h][1] = (f32x4){0,0,0,0}; }
    float M[8], L[8];
    #pragma unroll
    for (int h = 0; h < 8; ++h) { M[h] = -INFINITY; L[h] = 0.f; }

    #pragma unroll 1
    for (int m0 = 0; m0 < 64; m0 += 16) {
        const int mg = m_base + m0;

        // ---- aux loads for this step (positions: n=ln, m=qd*4+r) ----
        float ax[8][4];
        #pragma unroll
        for (int h = 0; h < 8; ++h)
            #pragma unroll
            for (int r = 0; r < 4; ++r)
                ax[h][r] = aux[(size_t)h * 4194304 + aux_base + mg + qd * 4 + r];

        // ---- scores (transposed): S^T = K·Q^T, C: (m=qd*4+r, n=ln) ----
        f32x4 C[8];
        #pragma unroll
        for (int h = 0; h < 8; ++h) {
            f16x8 kf = *(const f16x8*)(Kb + (((size_t)h * 16 + b) * ML + mg + ln) * 32 + qd * 8);
            f16x8 qf = *(const f16x8*)(Qb + (((size_t)h * 16 + b) * NR + n0 + ln) * 32 + qd * 8);
            C[h] = __builtin_amdgcn_mfma_f32_16x16x32_f16(kf, qf, (f32x4){0,0,0,0}, 0, 0, 0);
        }

        // ---- fuse MLP: 4 positions/lane, processed in 2 pairs ----
        float F[8][4];
        #pragma unroll
        for (int pr = 0; pr < 2; ++pr) {
            const int r0 = pr * 2, r1 = pr * 2 + 1;
            float h0[16], h1[16];
            #pragma unroll
            for (int j = 0; j < 16; ++j) { float bj = Wl[384 + j]; h0[j] = bj; h1[j] = bj; }
            #pragma unroll
            for (int i = 0; i < 16; ++i) {
                const float x0 = (i < 8) ? C[i][r0] : ax[i - 8][r0];
                const float x1 = (i < 8) ? C[i][r1] : ax[i - 8][r1];
                #pragma unroll
                for (int j = 0; j < 16; ++j) {
                    const float w = Wl[i * 16 + j];
                    h0[j] += x0 * w; h1[j] += x1 * w;
                }
            }
            float f0[8], f1[8];
            #pragma unroll
            for (int o = 0; o < 8; ++o) { float bo = Wl[400 + o]; f0[o] = bo; f1[o] = bo; }
            #pragma unroll
            for (int j = 0; j < 16; ++j) {
                const float g0 = fmaxf(h0[j], 0.f), g1 = fmaxf(h1[j], 0.f);
                #pragma unroll
                for (int o = 0; o < 8; ++o) {
                    const float w = Wl[256 + j * 8 + o];
                    f0[o] += g0 * w; f1[o] += g1 * w;
                }
            }
            #pragma unroll
            for (int o = 0; o < 8; ++o) { F[o][r0] = f0[o]; F[o][r1] = f1[o]; }
        }

        // ---- per-head online softmax (row n=ln; m over 4 in-lane + qd groups)
        //      + rescale + PV MFMA ----
        #pragma unroll
        for (int h = 0; h < 8; ++h) {
            float mx = fmaxf(fmaxf(F[h][0], F[h][1]), fmaxf(F[h][2], F[h][3]));
            mx = fmaxf(mx, __shfl_xor(mx, 16));
            mx = fmaxf(mx, __shfl_xor(mx, 32));
            const float nM = fmaxf(M[h], mx);
            const float al = __expf(M[h] - nM);
            M[h] = nM;
            const float p0 = __expf(F[h][0] - nM);
            const float p1 = __expf(F[h][1] - nM);
            const float p2 = __expf(F[h][2] - nM);
            const float p3 = __expf(F[h][3] - nM);
            float rs = p0 + p1 + p2 + p3;
            rs += __shfl_xor(rs, 16);
            rs += __shfl_xor(rs, 32);
            L[h] = L[h] * al + rs;
            const f16x4 pf = { (f16)p0, (f16)p1, (f16)p2, (f16)p3 };
            #pragma unroll
            for (int t = 0; t < 2; ++t) {
                f16x4 vf = *(const f16x4*)(Vt + (((size_t)h * 16 + b) * 32 + t * 16 + ln) * ML + mg + qd * 4);
                f32x4 cc = oacc[h][t];
                cc[0] *= al; cc[1] *= al; cc[2] *= al; cc[3] *= al;
                oacc[h][t] = __builtin_amdgcn_mfma_f32_16x16x16f16(vf, pf, cc, 0, 0, 0);
            }
        }
    }

    // ---- epilogue: O^T C-layout (e=qd*4+r, n=ln) -> o[n][e] f16 ----
    #pragma unroll
    for (int h = 0; h < 8; ++h) {
        #pragma unroll
        for (int t = 0; t < 2; ++t) {
            f16x4 ov = { (f16)oacc[h][t][0], (f16)oacc[h][t][1],
                         (f16)oacc[h][t][2], (f16)oacc[h][t][3] };
            *(f16x4*)(op + (((size_t)h * 16 + b) * NR + n0 + ln) * 32 + t * 16 + qd * 4) = ov;
        }
        if (qd == 0) {
            float2 ml = make_float2(M[h], L[h]);
            *(float2*)(mlo + (((size_t)h * 16 + b) * NR + n0 + ln) * 2) = ml;
        }
    }
}

// ---------------------------------------------------------------------------
// Combine: merge nchA key-chunks (shared softmax) + optional group-B partial
// (independent softmax, added). Writes HE[b][q_off+n][h*32+e] fp32.
// ---------------------------------------------------------------------------
__global__ __launch_bounds__(256)
void combine_kernel(const f16* __restrict__ oA, const float* __restrict__ mlA, int nchA,
                    const f16* __restrict__ oB, const float* __restrict__ mlB,
                    float* __restrict__ HE, int NR, int q_off)
{
    const int tid = (int)threadIdx.x;
    const int sn = tid >> 4, sh = (tid >> 1) & 7, smh = tid & 1;
    const int n = (int)blockIdx.x * 16 + sn;
    const int b = (int)blockIdx.y;

    float M = -INFINITY;
    for (int c = 0; c < nchA; ++c)
        M = fmaxf(M, mlA[((((size_t)c * 8 + sh) * 16 + b) * NR + n) * 2]);
    float L = 0.f;
    float o[16];
    #pragma unroll
    for (int j = 0; j < 16; ++j) o[j] = 0.f;
    for (int c = 0; c < nchA; ++c) {
        const size_t mlb = ((((size_t)c * 8 + sh) * 16 + b) * NR + n) * 2;
        const float w = __expf(mlA[mlb] - M);
        L += mlA[mlb + 1] * w;
        const f16* src = oA + ((((size_t)c * 8 + sh) * 16 + b) * NR + n) * 32 + smh * 16;
        #pragma unroll
        for (int j = 0; j < 16; ++j) o[j] += w * (float)src[j];
    }
    const float invL = 1.f / L;
    #pragma unroll
    for (int j = 0; j < 16; ++j) o[j] *= invL;

    if (oB != nullptr) {
        const float invB = 1.f / mlB[(((size_t)sh * 16 + b) * NR + n) * 2 + 1];
        const f16* src = oB + (((size_t)sh * 16 + b) * NR + n) * 32 + smh * 16;
        #pragma unroll
        for (int j = 0; j < 16; ++j) o[j] += invB * (float)src[j];
    }
    float* dst = HE + ((size_t)b * 512 + q_off + n) * 256 + sh * 32 + smh * 16;
    #pragma unroll
    for (int j4 = 0; j4 < 4; ++j4)
        *(float4*)(dst + j4 * 4) = make_float4(o[j4*4+0], o[j4*4+1], o[j4*4+2], o[j4*4+3]);
}

// ---------------------------------------------------------------------------
extern "C" void kernel_launch(void* const* d_in, const int* in_sizes, int n_in,
                              void* d_out, int out_size, void* d_ws, size_t ws_size,
                              hipStream_t stream)
{
    (void)in_sizes; (void)n_in; (void)out_size; (void)ws_size;

    const float* h_fea  = (const float*)d_in[0];
    const float* aux    = (const float*)d_in[1];
    const float* Wq_c   = (const float*)d_in[2];
    const float* Wq_c1  = (const float*)d_in[3];
    const float* Wk_c   = (const float*)d_in[4];
    const float* Wv_c   = (const float*)d_in[5];
    const float* Wq_ch1 = (const float*)d_in[6];
    const float* Wk_ch  = (const float*)d_in[7];
    const float* Wv_ch  = (const float*)d_in[8];
    const float* W1     = (const float*)d_in[9];
    const float* b1     = (const float*)d_in[10];
    const float* W2     = (const float*)d_in[11];
    const float* b2     = (const float*)d_in[12];
    const float* W_out  = (const float*)d_in[13];

    const size_t TBIG = (size_t)8 * 16 * 448 * 32;   // 1,835,008 elems
    const size_t TSML = (size_t)8 * 16 * 64 * 32;    //   262,144 elems
    char* wp = (char*)d_ws;
    auto alloc = [&](size_t bytes) { char* p = wp; wp += (bytes + 255) & ~(size_t)255; return p; };

    f16*   QT1 = (f16*)alloc(TBIG * 2);
    f16*   QT  = (f16*)alloc(TBIG * 2);
    f16*   KC  = (f16*)alloc(TBIG * 2);
    f16*   VCT = (f16*)alloc(TBIG * 2);              // V_c^T [h][b][e][448]
    f16*   QS  = (f16*)alloc(TSML * 2);
    f16*   KS  = (f16*)alloc(TSML * 2);
    f16*   VST = (f16*)alloc(TSML * 2);              // V_s^T [h][b][e][64]
    float* HE  = (float*)alloc((size_t)16 * 512 * 256 * 4);
    f16*   oA  = (f16*)alloc(7 * TBIG * 2);
    float* mlA = (float*)alloc((size_t)7 * 8 * 16 * 448 * 2 * 4);
    f16*   oB  = (f16*)alloc(TBIG * 2);
    float* mlB = (float*)alloc((size_t)8 * 16 * 448 * 2 * 4);
    f16*   oC  = (f16*)alloc(7 * TSML * 2);
    float* mlC = (float*)alloc((size_t)7 * 8 * 16 * 64 * 2 * 4);

    // Projections (task rows q 64..511, stat rows q 0..63); V outputs transposed
    proj_gemm<<<dim3(112, 16), 256, 0, stream>>>(h_fea, Wq_c1, Wq_c, Wk_c, Wv_c,
                                                 QT1, QT, KC, VCT, 64, 448, 7, 3);
    proj_gemm<<<dim3(16, 12), 256, 0, stream>>>(h_fea, Wq_ch1, Wk_ch, Wv_ch, Wv_ch,
                                                QS, KS, VST, VST, 0, 64, 1, 2);

    // Unified attend: 4032 waves (attend1 3136 | attend2 448 | attend3 448)
    attend_fused<<<dim3(1008), 256, 0, stream>>>(QT1, QT, QS, KC, VCT, KS, VST, aux,
                                                 W1, b1, W2, b2,
                                                 oA, mlA, oB, mlB, oC, mlC);

    // Combine
    combine_kernel<<<dim3(28, 16), 256, 0, stream>>>(oA, mlA, 7, oB, mlB, HE, 448, 64);
    combine_kernel<<<dim3(4, 16), 256, 0, stream>>>(oC, mlC, 7, nullptr, nullptr, HE, 64, 0);

    // h_wave = HEADS[8192,256] @ W_out[256,256]
    out_gemm<<<dim3(128, 4), 256, 0, stream>>>(HE, W_out, (float*)d_out);
}

// Round 6
// 733.979 us; speedup vs baseline: 2.0261x; 2.0261x over previous
//
#include <hip/hip_runtime.h>
#include <math.h>

// Shapes (fixed): H=8, D=256, HD=32, B=16, Q=512, S1=64, NTASK=448
typedef _Float16 f16;
typedef f16  f16x8 __attribute__((ext_vector_type(8)));
typedef f16  f16x4 __attribute__((ext_vector_type(4)));
typedef float f32x4 __attribute__((ext_vector_type(4)));

// ---------------------------------------------------------------------------
// Projection GEMM (fp32 compute, fp16 output).
// Normal outputs: [h][b][n][32] fp16 row-major.  V output (p==vt_p): V^T
// layout [h][b][e][NR] fp16 (contiguous m) for MFMA A-fragments.
// ---------------------------------------------------------------------------
__global__ __launch_bounds__(256)
void proj_gemm(const float* __restrict__ A,
               const float* __restrict__ W0, const float* __restrict__ W1p,
               const float* __restrict__ W2p, const float* __restrict__ W3p,
               f16* __restrict__ O0, f16* __restrict__ O1,
               f16* __restrict__ O2, f16* __restrict__ O3,
               int q_off, int rows_per_b, int tiles_per_b, int vt_p)
{
    __shared__ float Asub[32][68];
    __shared__ float Bsub[32][68];
    const int tid = (int)threadIdx.x;
    const int b  = (int)blockIdx.x / tiles_per_b;
    const int n0 = ((int)blockIdx.x % tiles_per_b) * 64;
    const int p  = (int)blockIdx.y >> 2;
    const int cb = ((int)blockIdx.y & 3) * 64;
    const float* Wp = (p == 0) ? W0 : (p == 1) ? W1p : (p == 2) ? W2p : W3p;
    f16* Op         = (p == 0) ? O0 : (p == 1) ? O1 : (p == 2) ? O2 : O3;

    const int tx = tid & 15, ty = tid >> 4;
    float acc[4][4] = {};
    const float* Arow = A + (size_t)(b * 512 + q_off + n0) * 256;

    for (int k0 = 0; k0 < 256; k0 += 32) {
        #pragma unroll
        for (int i = 0; i < 8; ++i) {
            int idx = tid + 256 * i;
            int kk = idx & 31, r = idx >> 5;
            Asub[kk][r] = Arow[(size_t)r * 256 + k0 + kk];
        }
        #pragma unroll
        for (int i = 0; i < 8; ++i) {
            int idx = tid + 256 * i;
            int c = idx & 63, kk = idx >> 6;
            int cg = cb + c;
            int h = cg >> 5, e = cg & 31;
            Bsub[kk][c] = Wp[(size_t)(h * 256 + k0 + kk) * 32 + e];
        }
        __syncthreads();
        #pragma unroll
        for (int kk = 0; kk < 32; ++kk) {
            float4 a4 = *(const float4*)&Asub[kk][ty * 4];
            float4 b4 = *(const float4*)&Bsub[kk][tx * 4];
            acc[0][0] += a4.x * b4.x; acc[0][1] += a4.x * b4.y; acc[0][2] += a4.x * b4.z; acc[0][3] += a4.x * b4.w;
            acc[1][0] += a4.y * b4.x; acc[1][1] += a4.y * b4.y; acc[1][2] += a4.y * b4.z; acc[1][3] += a4.y * b4.w;
            acc[2][0] += a4.z * b4.x; acc[2][1] += a4.z * b4.y; acc[2][2] += a4.z * b4.z; acc[2][3] += a4.z * b4.w;
            acc[3][0] += a4.w * b4.x; acc[3][1] += a4.w * b4.y; acc[3][2] += a4.w * b4.z; acc[3][3] += a4.w * b4.w;
        }
        __syncthreads();
    }
    const int cg = cb + tx * 4;
    const int h = cg >> 5, e = cg & 31;
    if (p == vt_p) {
        #pragma unroll
        for (int i = 0; i < 4; ++i) {
            int n = n0 + ty * 4 + i;
            #pragma unroll
            for (int j = 0; j < 4; ++j)
                Op[(((size_t)h * 16 + b) * 32 + e + j) * rows_per_b + n] = (f16)acc[i][j];
        }
    } else {
        #pragma unroll
        for (int i = 0; i < 4; ++i) {
            int n = n0 + ty * 4 + i;
            f16x4 v = { (f16)acc[i][0], (f16)acc[i][1], (f16)acc[i][2], (f16)acc[i][3] };
            *(f16x4*)&Op[(((size_t)h * 16 + b) * rows_per_b + n) * 32 + e] = v;
        }
    }
}

// ---------------------------------------------------------------------------
// Output projection: C[bq][d] = HEADS[8192,256] @ W_out[256,256]  (fp32)
// ---------------------------------------------------------------------------
__global__ __launch_bounds__(256)
void out_gemm(const float* __restrict__ A, const float* __restrict__ Bm,
              float* __restrict__ C)
{
    __shared__ float Asub[32][68];
    __shared__ float Bsub[32][68];
    const int tid = (int)threadIdx.x;
    const int row0 = (int)blockIdx.x * 64;
    const int col0 = (int)blockIdx.y * 64;
    const int tx = tid & 15, ty = tid >> 4;
    float acc[4][4] = {};

    for (int k0 = 0; k0 < 256; k0 += 32) {
        #pragma unroll
        for (int i = 0; i < 8; ++i) {
            int idx = tid + 256 * i;
            int kk = idx & 31, r = idx >> 5;
            Asub[kk][r] = A[(size_t)(row0 + r) * 256 + k0 + kk];
        }
        #pragma unroll
        for (int i = 0; i < 8; ++i) {
            int idx = tid + 256 * i;
            int c = idx & 63, kk = idx >> 6;
            Bsub[kk][c] = Bm[(size_t)(k0 + kk) * 256 + col0 + c];
        }
        __syncthreads();
        #pragma unroll
        for (int kk = 0; kk < 32; ++kk) {
            float4 a4 = *(const float4*)&Asub[kk][ty * 4];
            float4 b4 = *(const float4*)&Bsub[kk][tx * 4];
            acc[0][0] += a4.x * b4.x; acc[0][1] += a4.x * b4.y; acc[0][2] += a4.x * b4.z; acc[0][3] += a4.x * b4.w;
            acc[1][0] += a4.y * b4.x; acc[1][1] += a4.y * b4.y; acc[1][2] += a4.y * b4.z; acc[1][3] += a4.y * b4.w;
            acc[2][0] += a4.z * b4.x; acc[2][1] += a4.z * b4.y; acc[2][2] += a4.z * b4.z; acc[2][3] += a4.z * b4.w;
            acc[3][0] += a4.w * b4.x; acc[3][1] += a4.w * b4.y; acc[3][2] += a4.w * b4.z; acc[3][3] += a4.w * b4.w;
        }
        __syncthreads();
    }
    #pragma unroll
    for (int i = 0; i < 4; ++i) {
        float4 v = make_float4(acc[i][0], acc[i][1], acc[i][2], acc[i][3]);
        *(float4*)&C[(size_t)(row0 + ty * 4 + i) * 256 + col0 + tx * 4] = v;
    }
}

// ---------------------------------------------------------------------------
// Unified wave-autonomous attend. One WAVE = one (n-tile, b, 64-key chunk).
// No barriers in the K-loop. The 4 waves of a block share (chunk, b) so K/V
// slices are L1/L2-resident.  Scores computed transposed: S^T = K·Q^T, so the
// C-layout (n=lane&15, m=qd*4+r) is directly the B-fragment for O^T = V^T·P.
// MLP outputs overwrite the score regs C[o][r] (register-pressure control:
// peak live ~210 VGPR, no launch_bounds min-waves so the allocator can take
// them — the round-5 spill catastrophe came from a 128-VGPR cap).
// ---------------------------------------------------------------------------
__global__ __launch_bounds__(256)
void attend_fused(const f16* __restrict__ QT1, const f16* __restrict__ QT,
                  const f16* __restrict__ QS,  const f16* __restrict__ KC,
                  const f16* __restrict__ VCT, const f16* __restrict__ KS,
                  const f16* __restrict__ VST, const float* __restrict__ aux,
                  const float* __restrict__ W1g, const float* __restrict__ b1g,
                  const float* __restrict__ W2g, const float* __restrict__ b2g,
                  f16* __restrict__ oA, float* __restrict__ mlA,
                  f16* __restrict__ oB, float* __restrict__ mlB,
                  f16* __restrict__ oC, float* __restrict__ mlC)
{
    __shared__ float Wl[408];   // W1(256) | W2(128) | b1(16) | b2(8)
    const int tid = (int)threadIdx.x;
    Wl[tid] = W1g[tid];
    if (tid < 128) Wl[256 + tid] = W2g[tid];
    if (tid < 16)  Wl[384 + tid] = b1g[tid];
    if (tid < 8)   Wl[400 + tid] = b2g[tid];
    __syncthreads();

    const int blk  = (int)blockIdx.x;
    const int ws   = tid >> 6;         // wave slot in block
    const int lane = tid & 63;
    const int ln   = lane & 15;        // row n within tile
    const int qd   = lane >> 4;        // quad: m = qd*4+r (scores), e = qd*4+r (O^T)

    // ---- decode work item (waves in a block share (chunk, b)) ----
    const f16 *Qb, *Kb, *Vt;
    f16* op; float* mlo;
    int NR, ML, n_off, m_off, m_base, n0, b;
    if (blk < 784) {                        // attend1: task q vs task k
        int c = blk / 112, r = blk % 112;
        int g = r >> 4; b = r & 15;
        n0 = (g * 4 + ws) * 16;
        Qb = QT1; Kb = KC; Vt = VCT; NR = 448; ML = 448; n_off = 64; m_off = 64;
        m_base = c * 64;
        op  = oA  + (size_t)c * 8 * 16 * 448 * 32;
        mlo = mlA + (size_t)c * 8 * 16 * 448 * 2;
    } else if (blk < 896) {                 // attend2: task q vs stat k
        int r = blk - 784;
        int g = r >> 4; b = r & 15;
        n0 = (g * 4 + ws) * 16;
        Qb = QT; Kb = KS; Vt = VST; NR = 448; ML = 64; n_off = 64; m_off = 0;
        m_base = 0;
        op = oB; mlo = mlB;
    } else {                                // attend3: stat q vs task k
        int r = blk - 896;
        int c = r >> 4; b = r & 15;
        n0 = ws * 16;
        Qb = QS; Kb = KC; Vt = VCT; NR = 64; ML = 448; n_off = 0; m_off = 64;
        m_base = c * 64;
        op  = oC  + (size_t)c * 8 * 16 * 64 * 32;
        mlo = mlC + (size_t)c * 8 * 16 * 64 * 2;
    }

    const size_t aux_base = ((size_t)b * 512 + (n_off + n0 + ln)) * 512 + m_off;

    f32x4 oacc[8][2];
    #pragma unroll
    for (int h = 0; h < 8; ++h) { oacc[h][0] = (f32x4){0,0,0,0}; oacc[h][1] = (f32x4){0,0,0,0}; }
    float M[8], L[8];
    #pragma unroll
    for (int h = 0; h < 8; ++h) { M[h] = -INFINITY; L[h] = 0.f; }

    #pragma unroll 1
    for (int m0 = 0; m0 < 64; m0 += 16) {
        const int mg = m_base + m0;

        // ---- aux loads for this step (positions: n=ln, m=qd*4+r) ----
        float ax[8][4];
        #pragma unroll
        for (int h = 0; h < 8; ++h)
            #pragma unroll
            for (int r = 0; r < 4; ++r)
                ax[h][r] = aux[(size_t)h * 4194304 + aux_base + mg + qd * 4 + r];

        // ---- scores (transposed): S^T = K·Q^T, C: (m=qd*4+r, n=ln) ----
        f32x4 C[8];
        #pragma unroll
        for (int h = 0; h < 8; ++h) {
            f16x8 kf = *(const f16x8*)(Kb + (((size_t)h * 16 + b) * ML + mg + ln) * 32 + qd * 8);
            f16x8 qf = *(const f16x8*)(Qb + (((size_t)h * 16 + b) * NR + n0 + ln) * 32 + qd * 8);
            C[h] = __builtin_amdgcn_mfma_f32_16x16x32_f16(kf, qf, (f32x4){0,0,0,0}, 0, 0, 0);
        }

        // ---- fuse MLP (2 pairs of positions); outputs overwrite C[o][r] ----
        #pragma unroll
        for (int pr = 0; pr < 2; ++pr) {
            const int r0 = pr * 2, r1 = pr * 2 + 1;
            float h0[16], h1[16];
            #pragma unroll
            for (int j = 0; j < 16; ++j) { float bj = Wl[384 + j]; h0[j] = bj; h1[j] = bj; }
            #pragma unroll
            for (int i = 0; i < 16; ++i) {
                const float x0 = (i < 8) ? C[i][r0] : ax[i - 8][r0];
                const float x1 = (i < 8) ? C[i][r1] : ax[i - 8][r1];
                #pragma unroll
                for (int j = 0; j < 16; ++j) {
                    const float w = Wl[i * 16 + j];
                    h0[j] += x0 * w; h1[j] += x1 * w;
                }
            }
            float f0[8], f1[8];
            #pragma unroll
            for (int o = 0; o < 8; ++o) { float bo = Wl[400 + o]; f0[o] = bo; f1[o] = bo; }
            #pragma unroll
            for (int j = 0; j < 16; ++j) {
                const float g0 = fmaxf(h0[j], 0.f), g1 = fmaxf(h1[j], 0.f);
                #pragma unroll
                for (int o = 0; o < 8; ++o) {
                    const float w = Wl[256 + j * 8 + o];
                    f0[o] += g0 * w; f1[o] += g1 * w;
                }
            }
            #pragma unroll
            for (int o = 0; o < 8; ++o) { C[o][r0] = f0[o]; C[o][r1] = f1[o]; }
        }

        // ---- per-head online softmax + rescale + PV MFMA ----
        #pragma unroll
        for (int h = 0; h < 8; ++h) {
            float mx = fmaxf(fmaxf(C[h][0], C[h][1]), fmaxf(C[h][2], C[h][3]));
            mx = fmaxf(mx, __shfl_xor(mx, 16));
            mx = fmaxf(mx, __shfl_xor(mx, 32));
            const float nM = fmaxf(M[h], mx);
            const float al = __expf(M[h] - nM);
            M[h] = nM;
            const float p0 = __expf(C[h][0] - nM);
            const float p1 = __expf(C[h][1] - nM);
            const float p2 = __expf(C[h][2] - nM);
            const float p3 = __expf(C[h][3] - nM);
            float rs = p0 + p1 + p2 + p3;
            rs += __shfl_xor(rs, 16);
            rs += __shfl_xor(rs, 32);
            L[h] = L[h] * al + rs;
            const f16x4 pf = { (f16)p0, (f16)p1, (f16)p2, (f16)p3 };
            #pragma unroll
            for (int t = 0; t < 2; ++t) {
                f16x4 vf = *(const f16x4*)(Vt + (((size_t)h * 16 + b) * 32 + t * 16 + ln) * ML + mg + qd * 4);
                f32x4 cc = oacc[h][t];
                cc[0] *= al; cc[1] *= al; cc[2] *= al; cc[3] *= al;
                oacc[h][t] = __builtin_amdgcn_mfma_f32_16x16x16f16(vf, pf, cc, 0, 0, 0);
            }
        }
    }

    // ---- epilogue: O^T C-layout (e=qd*4+r, n=ln) -> o[n][e] f16 ----
    #pragma unroll
    for (int h = 0; h < 8; ++h) {
        #pragma unroll
        for (int t = 0; t < 2; ++t) {
            f16x4 ov = { (f16)oacc[h][t][0], (f16)oacc[h][t][1],
                         (f16)oacc[h][t][2], (f16)oacc[h][t][3] };
            *(f16x4*)(op + (((size_t)h * 16 + b) * NR + n0 + ln) * 32 + t * 16 + qd * 4) = ov;
        }
        if (qd == 0) {
            float2 ml = make_float2(M[h], L[h]);
            *(float2*)(mlo + (((size_t)h * 16 + b) * NR + n0 + ln) * 2) = ml;
        }
    }
}

// ---------------------------------------------------------------------------
// Combine: merge nchA key-chunks (shared softmax) + optional group-B partial
// (independent softmax, added). Writes HE[b][q_off+n][h*32+e] fp32.
// ---------------------------------------------------------------------------
__global__ __launch_bounds__(256)
void combine_kernel(const f16* __restrict__ oA, const float* __restrict__ mlA, int nchA,
                    const f16* __restrict__ oB, const float* __restrict__ mlB,
                    float* __restrict__ HE, int NR, int q_off)
{
    const int tid = (int)threadIdx.x;
    const int sn = tid >> 4, sh = (tid >> 1) & 7, smh = tid & 1;
    const int n = (int)blockIdx.x * 16 + sn;
    const int b = (int)blockIdx.y;

    float M = -INFINITY;
    for (int c = 0; c < nchA; ++c)
        M = fmaxf(M, mlA[((((size_t)c * 8 + sh) * 16 + b) * NR + n) * 2]);
    float L = 0.f;
    float o[16];
    #pragma unroll
    for (int j = 0; j < 16; ++j) o[j] = 0.f;
    for (int c = 0; c < nchA; ++c) {
        const size_t mlb = ((((size_t)c * 8 + sh) * 16 + b) * NR + n) * 2;
        const float w = __expf(mlA[mlb] - M);
        L += mlA[mlb + 1] * w;
        const f16* src = oA + ((((size_t)c * 8 + sh) * 16 + b) * NR + n) * 32 + smh * 16;
        #pragma unroll
        for (int j = 0; j < 16; ++j) o[j] += w * (float)src[j];
    }
    const float invL = 1.f / L;
    #pragma unroll
    for (int j = 0; j < 16; ++j) o[j] *= invL;

    if (oB != nullptr) {
        const float invB = 1.f / mlB[(((size_t)sh * 16 + b) * NR + n) * 2 + 1];
        const f16* src = oB + (((size_t)sh * 16 + b) * NR + n) * 32 + smh * 16;
        #pragma unroll
        for (int j = 0; j < 16; ++j) o[j] += invB * (float)src[j];
    }
    float* dst = HE + ((size_t)b * 512 + q_off + n) * 256 + sh * 32 + smh * 16;
    #pragma unroll
    for (int j4 = 0; j4 < 4; ++j4)
        *(float4*)(dst + j4 * 4) = make_float4(o[j4*4+0], o[j4*4+1], o[j4*4+2], o[j4*4+3]);
}

// ---------------------------------------------------------------------------
extern "C" void kernel_launch(void* const* d_in, const int* in_sizes, int n_in,
                              void* d_out, int out_size, void* d_ws, size_t ws_size,
                              hipStream_t stream)
{
    (void)in_sizes; (void)n_in; (void)out_size; (void)ws_size;

    const float* h_fea  = (const float*)d_in[0];
    const float* aux    = (const float*)d_in[1];
    const float* Wq_c   = (const float*)d_in[2];
    const float* Wq_c1  = (const float*)d_in[3];
    const float* Wk_c   = (const float*)d_in[4];
    const float* Wv_c   = (const float*)d_in[5];
    const float* Wq_ch1 = (const float*)d_in[6];
    const float* Wk_ch  = (const float*)d_in[7];
    const float* Wv_ch  = (const float*)d_in[8];
    const float* W1     = (const float*)d_in[9];
    const float* b1     = (const float*)d_in[10];
    const float* W2     = (const float*)d_in[11];
    const float* b2     = (const float*)d_in[12];
    const float* W_out  = (const float*)d_in[13];

    const size_t TBIG = (size_t)8 * 16 * 448 * 32;   // 1,835,008 elems
    const size_t TSML = (size_t)8 * 16 * 64 * 32;    //   262,144 elems
    char* wp = (char*)d_ws;
    auto alloc = [&](size_t bytes) { char* p = wp; wp += (bytes + 255) & ~(size_t)255; return p; };

    f16*   QT1 = (f16*)alloc(TBIG * 2);
    f16*   QT  = (f16*)alloc(TBIG * 2);
    f16*   KC  = (f16*)alloc(TBIG * 2);
    f16*   VCT = (f16*)alloc(TBIG * 2);              // V_c^T [h][b][e][448]
    f16*   QS  = (f16*)alloc(TSML * 2);
    f16*   KS  = (f16*)alloc(TSML * 2);
    f16*   VST = (f16*)alloc(TSML * 2);              // V_s^T [h][b][e][64]
    float* HE  = (float*)alloc((size_t)16 * 512 * 256 * 4);
    f16*   oA  = (f16*)alloc(7 * TBIG * 2);
    float* mlA = (float*)alloc((size_t)7 * 8 * 16 * 448 * 2 * 4);
    f16*   oB  = (f16*)alloc(TBIG * 2);
    float* mlB = (float*)alloc((size_t)8 * 16 * 448 * 2 * 4);
    f16*   oC  = (f16*)alloc(7 * TSML * 2);
    float* mlC = (float*)alloc((size_t)7 * 8 * 16 * 64 * 2 * 4);

    // Projections (task rows q 64..511, stat rows q 0..63); V outputs transposed
    proj_gemm<<<dim3(112, 16), 256, 0, stream>>>(h_fea, Wq_c1, Wq_c, Wk_c, Wv_c,
                                                 QT1, QT, KC, VCT, 64, 448, 7, 3);
    proj_gemm<<<dim3(16, 12), 256, 0, stream>>>(h_fea, Wq_ch1, Wk_ch, Wv_ch, Wv_ch,
                                                QS, KS, VST, VST, 0, 64, 1, 2);

    // Unified attend: 1008 blocks x 4 waves (attend1 784 | attend2 112 | attend3 112)
    attend_fused<<<dim3(1008), 256, 0, stream>>>(QT1, QT, QS, KC, VCT, KS, VST, aux,
                                                 W1, b1, W2, b2,
                                                 oA, mlA, oB, mlB, oC, mlC);

    // Combine
    combine_kernel<<<dim3(28, 16), 256, 0, stream>>>(oA, mlA, 7, oB, mlB, HE, 448, 64);
    combine_kernel<<<dim3(4, 16), 256, 0, stream>>>(oC, mlC, 7, nullptr, nullptr, HE, 64, 0);

    // h_wave = HEADS[8192,256] @ W_out[256,256]
    out_gemm<<<dim3(128, 4), 256, 0, stream>>>(HE, W_out, (float*)d_out);
}